// Round 1
// baseline (263.052 us; speedup 1.0000x reference)
//
#include <hip/hip_runtime.h>
#include <hip/hip_bf16.h>
#include <math.h>

#define Bb 256
#define Nn 2048
#define Cc 128
#define Hh 64
#define Mm 50

// ---------------- K1: per-batch feat @ W1[:128] + b1 ----------------
__global__ __launch_bounds__(64) void k_base(const float* __restrict__ feat,
                                             const float* __restrict__ w1,
                                             const float* __restrict__ b1,
                                             float* __restrict__ base) {
    int b = blockIdx.x, k = threadIdx.x;
    const float* f = feat + b * Cc;
    float s = b1[k];
    #pragma unroll 8
    for (int c = 0; c < Cc; ++c) s = fmaf(f[c], w1[c * Hh + k], s);
    base[b * Hh + k] = s;
}

// ---------------- shared MLP body: layer1(reduced)+LN+ReLU, layer2, +b2, LN stats ----------------
__device__ __forceinline__ void mlp_hidden(
    float* __restrict__ t1c,            // &t1s[0][tid]; element j at t1c[j*128]
    float cx, float cy,
    const float* __restrict__ basev,    // per-batch base (64)
    const float* __restrict__ w1,       // (130,64); rows 128,129 used
    const float* __restrict__ g1, const float* __restrict__ be1,
    const float* __restrict__ w2, const float* __restrict__ b2,
    float acc[Hh], float& mu2o, float& rstd2o)
{
    const float* u = w1 + 128 * Hh;
    const float* v = w1 + 129 * Hh;
    float sum = 0.f, sq = 0.f;
    for (int j = 0; j < Hh; ++j) {
        float t = fmaf(cy, v[j], fmaf(cx, u[j], basev[j]));
        sum += t;
        sq = fmaf(t, t, sq);
        t1c[j * 128] = t;
    }
    float mu = sum * (1.f / Hh);
    float var = sq * (1.f / Hh) - mu * mu;
    float rstd = rsqrtf(var + 1e-5f);
    #pragma unroll
    for (int i = 0; i < Hh; ++i) acc[i] = 0.f;
    for (int j = 0; j < Hh; ++j) {
        float t = t1c[j * 128];
        float a = fmaxf(fmaf((t - mu) * rstd, g1[j], be1[j]), 0.f);
        const float* w2r = w2 + j * Hh;
        #pragma unroll
        for (int i = 0; i < Hh; ++i) acc[i] = fmaf(a, w2r[i], acc[i]);
    }
    float sum2 = 0.f, sq2 = 0.f;
    #pragma unroll
    for (int i = 0; i < Hh; ++i) {
        float h = acc[i] + b2[i];
        acc[i] = h;
        sum2 += h;
        sq2 = fmaf(h, h, sq2);
    }
    float mu2 = sum2 * (1.f / Hh);
    float rstd2 = rsqrtf(sq2 * (1.f / Hh) - mu2 * mu2 + 1e-5f);
    mu2o = mu2;
    rstd2o = rstd2;
}

// ---------------- K2: main per-row MLPs ----------------
__global__ __launch_bounds__(128) void k_mlp(
    const float* __restrict__ cand,
    const float* __restrict__ basep, const float* __restrict__ baseo,
    const float* __restrict__ p_w1, const float* __restrict__ p_g1, const float* __restrict__ p_be1,
    const float* __restrict__ p_w2, const float* __restrict__ p_b2,
    const float* __restrict__ p_g2, const float* __restrict__ p_be2,
    const float* __restrict__ p_w3, const float* __restrict__ p_b3,
    const float* __restrict__ o_w1, const float* __restrict__ o_g1, const float* __restrict__ o_be1,
    const float* __restrict__ o_w2, const float* __restrict__ o_b2,
    const float* __restrict__ o_g2, const float* __restrict__ o_be2,
    const float* __restrict__ o_w3, const float* __restrict__ o_b3,
    float* __restrict__ logits, float* __restrict__ offs)
{
    __shared__ float t1s[Hh][128];      // per-thread runtime-indexed layer1 acts
    int tid = threadIdx.x;
    int b = blockIdx.x >> 4;            // 16 blocks x 128 threads = 2048 rows per batch
    int n = ((blockIdx.x & 15) << 7) + tid;
    long row = (long)b * Nn + n;
    float cx = cand[row * 2 + 0];
    float cy = cand[row * 2 + 1];
    float* t1c = &t1s[0][tid];
    float acc[Hh];
    float mu2, rstd2;

    // probability MLP -> logit
    mlp_hidden(t1c, cx, cy, basep + b * Hh, p_w1, p_g1, p_be1, p_w2, p_b2, acc, mu2, rstd2);
    float lg = p_b3[0];
    #pragma unroll
    for (int i = 0; i < Hh; ++i) {
        float a = fmaxf(fmaf((acc[i] - mu2) * rstd2, p_g2[i], p_be2[i]), 0.f);
        lg = fmaf(a, p_w3[i], lg);
    }
    logits[row] = lg;

    // offset MLP -> (o0, o1)
    mlp_hidden(t1c, cx, cy, baseo + b * Hh, o_w1, o_g1, o_be1, o_w2, o_b2, acc, mu2, rstd2);
    float o0 = o_b3[0], o1 = o_b3[1];
    #pragma unroll
    for (int i = 0; i < Hh; ++i) {
        float a = fmaxf(fmaf((acc[i] - mu2) * rstd2, o_g2[i], o_be2[i]), 0.f);
        o0 = fmaf(a, o_w3[i * 2 + 0], o0);
        o1 = fmaf(a, o_w3[i * 2 + 1], o1);
    }
    offs[row * 2 + 0] = o0;
    offs[row * 2 + 1] = o1;
}

// ---------------- K3: per-batch softmax + BCE partial + smooth-L1 partial ----------------
__global__ __launch_bounds__(256) void k_softmax(
    const float* __restrict__ logits, const float* __restrict__ mask,
    const float* __restrict__ gt, const float* __restrict__ offs,
    const float* __restrict__ off_gt,
    float* __restrict__ p, float* __restrict__ bce_part, float* __restrict__ sl1_part)
{
    __shared__ float red[256];
    __shared__ int redi[256];
    int b = blockIdx.x, tid = threadIdx.x;
    const float* lg = logits + (long)b * Nn;
    const float* mk = mask + (long)b * Nn;
    float xv[8];
    float mx = -1e30f;
    #pragma unroll
    for (int k = 0; k < 8; ++k) {
        int n = tid + k * 256;
        xv[k] = lg[n] + mk[n];
        mx = fmaxf(mx, xv[k]);
    }
    red[tid] = mx; __syncthreads();
    for (int s = 128; s > 0; s >>= 1) { if (tid < s) red[tid] = fmaxf(red[tid], red[tid + s]); __syncthreads(); }
    float m = red[0]; __syncthreads();

    float ev[8]; float es = 0.f;
    #pragma unroll
    for (int k = 0; k < 8; ++k) { ev[k] = expf(xv[k] - m); es += ev[k]; }
    red[tid] = es; __syncthreads();
    for (int s = 128; s > 0; s >>= 1) { if (tid < s) red[tid] += red[tid + s]; __syncthreads(); }
    float invZ = 1.f / red[0]; __syncthreads();

    const float* g = gt + (long)b * Nn;
    float bs = 0.f;
    int gidx = 0x7fffffff;
    #pragma unroll
    for (int k = 0; k < 8; ++k) {
        int n = tid + k * 256;
        float pv = ev[k] * invZ;
        p[(long)b * Nn + n] = pv;
        float gv = g[n];
        float lp = fmaxf(logf(pv), -100.f);
        float l1p = fmaxf(log1pf(-pv), -100.f);
        bs += gv * lp + (1.f - gv) * l1p;
        if (gv > 0.5f) gidx = min(gidx, n);
    }
    red[tid] = bs; redi[tid] = gidx; __syncthreads();
    for (int s = 128; s > 0; s >>= 1) {
        if (tid < s) { red[tid] += red[tid + s]; redi[tid] = min(redi[tid], redi[tid + s]); }
        __syncthreads();
    }
    if (tid == 0) {
        bce_part[b] = red[0];
        int gi = redi[0];
        float s1 = 0.f;
        #pragma unroll
        for (int c = 0; c < 2; ++c) {
            float d = offs[((long)b * Nn + gi) * 2 + c] - off_gt[b * 2 + c];
            float ad = fabsf(d);
            s1 += (ad < 1.f) ? 0.5f * d * d : ad - 0.5f;
        }
        sl1_part[b] = s1;
    }
}

// ---------------- K4: per-batch top-50 (exact lax.top_k order) + gather + NMS ----------------
__global__ __launch_bounds__(256) void k_topk(
    const float* __restrict__ p, const float* __restrict__ cand,
    const float* __restrict__ offs, float* __restrict__ out)
{
    __shared__ float vals[Nn];
    __shared__ float rv[256];
    __shared__ int ri[256];
    __shared__ float tx[Mm], ty[Mm];
    __shared__ int selidx[Mm];
    int b = blockIdx.x, tid = threadIdx.x;
    #pragma unroll
    for (int k = 0; k < 8; ++k) { int n = tid + k * 256; vals[n] = p[(long)b * Nn + n]; }
    __syncthreads();
    for (int it = 0; it < Mm; ++it) {
        float bv = -1.f; int bi = Nn;
        #pragma unroll
        for (int k = 0; k < 8; ++k) {
            int n = tid + k * 256;          // ascending n per thread -> min idx kept on ties
            float v = vals[n];
            if (v > bv) { bv = v; bi = n; }
        }
        rv[tid] = bv; ri[tid] = bi; __syncthreads();
        for (int s = 128; s > 0; s >>= 1) {
            if (tid < s) {
                float v2 = rv[tid + s]; int i2 = ri[tid + s];
                if (v2 > rv[tid] || (v2 == rv[tid] && i2 < ri[tid])) { rv[tid] = v2; ri[tid] = i2; }
            }
            __syncthreads();
        }
        if (tid == 0) { selidx[it] = ri[0]; vals[ri[0]] = -1.f; }
        __syncthreads();
    }
    if (tid < Mm) {
        int idx = selidx[tid];
        long r = (long)b * Nn + idx;
        tx[tid] = cand[r * 2 + 0] + offs[r * 2 + 0];
        ty[tid] = cand[r * 2 + 1] + offs[r * 2 + 1];
    }
    __syncthreads();
    if (tid == 0) {
        float sx[6], sy[6];
        #pragma unroll
        for (int k = 0; k < 6; ++k) { sx[k] = tx[k]; sy[k] = ty[k]; }
        int cnt = 1;
        for (int i = 1; i < Mm; ++i) {
            bool close = false;
            #pragma unroll
            for (int k = 0; k < 6; ++k) {
                float dx = sx[k] - tx[i], dy = sy[k] - ty[i];
                close = close || ((k < cnt) && (dx * dx + dy * dy < 2.0f));
            }
            if (!close && cnt < 6) { sx[cnt] = tx[i]; sy[cnt] = ty[i]; cnt++; }
        }
        #pragma unroll
        for (int k = 0; k < 6; ++k) {
            out[(b * 6 + k) * 2 + 0] = sx[k];
            out[(b * 6 + k) * 2 + 1] = sy[k];
        }
    }
}

// ---------------- K5: final loss ----------------
__global__ void k_loss(const float* __restrict__ bce_part, const float* __restrict__ sl1_part,
                       float* __restrict__ out) {
    if (threadIdx.x == 0 && blockIdx.x == 0) {
        float sb = 0.f, ss = 0.f;
        for (int b = 0; b < Bb; ++b) { sb += bce_part[b]; ss += sl1_part[b]; }
        out[0] = -sb / (float)(Bb * Nn) + ss / (float)(Bb * 2);
    }
}

extern "C" void kernel_launch(void* const* d_in, const int* in_sizes, int n_in,
                              void* d_out, int out_size, void* d_ws, size_t ws_size,
                              hipStream_t stream) {
    const float* feat  = (const float*)d_in[0];
    const float* cand  = (const float*)d_in[1];
    const float* mask  = (const float*)d_in[2];
    const float* gt    = (const float*)d_in[3];
    const float* ogt   = (const float*)d_in[4];
    const float* p_w1  = (const float*)d_in[5];
    const float* p_b1  = (const float*)d_in[6];
    const float* p_g1  = (const float*)d_in[7];
    const float* p_be1 = (const float*)d_in[8];
    const float* p_w2  = (const float*)d_in[9];
    const float* p_b2  = (const float*)d_in[10];
    const float* p_g2  = (const float*)d_in[11];
    const float* p_be2 = (const float*)d_in[12];
    const float* p_w3  = (const float*)d_in[13];
    const float* p_b3  = (const float*)d_in[14];
    const float* o_w1  = (const float*)d_in[15];
    const float* o_b1  = (const float*)d_in[16];
    const float* o_g1  = (const float*)d_in[17];
    const float* o_be1 = (const float*)d_in[18];
    const float* o_w2  = (const float*)d_in[19];
    const float* o_g2  = (const float*)d_in[20];   // NOTE: dict order puts o_g2 before o_b2
    const float* o_b2  = (const float*)d_in[21];
    const float* o_be2 = (const float*)d_in[22];
    const float* o_w3  = (const float*)d_in[23];
    const float* o_b3  = (const float*)d_in[24];

    float* ws       = (float*)d_ws;
    float* basep    = ws;                     // B*H
    float* baseo    = basep + Bb * Hh;        // B*H
    float* logits   = baseo + Bb * Hh;        // B*N
    float* pbuf     = logits + Bb * Nn;       // B*N
    float* offs     = pbuf + Bb * Nn;         // B*N*2
    float* bce_part = offs + (long)Bb * Nn * 2; // B
    float* sl1_part = bce_part + Bb;          // B

    float* out = (float*)d_out;               // (B,6,2) floats then loss scalar

    k_base<<<Bb, Hh, 0, stream>>>(feat, p_w1, p_b1, basep);
    k_base<<<Bb, Hh, 0, stream>>>(feat, o_w1, o_b1, baseo);
    k_mlp<<<Bb * 16, 128, 0, stream>>>(cand, basep, baseo,
        p_w1, p_g1, p_be1, p_w2, p_b2, p_g2, p_be2, p_w3, p_b3,
        o_w1, o_g1, o_be1, o_w2, o_b2, o_g2, o_be2, o_w3, o_b3,
        logits, offs);
    k_softmax<<<Bb, 256, 0, stream>>>(logits, mask, gt, offs, ogt, pbuf, bce_part, sl1_part);
    k_topk<<<Bb, 256, 0, stream>>>(pbuf, cand, offs, out);
    k_loss<<<1, 1, 0, stream>>>(bce_part, sl1_part, out + Bb * 6 * 2);
}

// Round 2
// 193.873 us; speedup vs baseline: 1.3568x; 1.3568x over previous
//
#include <hip/hip_runtime.h>
#include <hip/hip_bf16.h>
#include <math.h>

#define Bb 256
#define Nn 2048
#define Cc 128
#define Hh 64
#define Mm 50

// ---------------- K1: per-batch feat @ W1[:128] + b1 for BOTH MLPs ----------------
__global__ __launch_bounds__(128) void k_base(const float* __restrict__ feat,
                                              const float* __restrict__ p_w1,
                                              const float* __restrict__ p_b1,
                                              const float* __restrict__ o_w1,
                                              const float* __restrict__ o_b1,
                                              float* __restrict__ basep,
                                              float* __restrict__ baseo) {
    int b = blockIdx.x, tid = threadIdx.x;
    int k = tid & 63;
    bool lo = tid < 64;                     // wave-uniform select
    const float* w1 = lo ? p_w1 : o_w1;
    const float* b1 = lo ? p_b1 : o_b1;
    float* dst = lo ? basep : baseo;
    const float* f = feat + b * Cc;
    float s = b1[k];
    #pragma unroll 8
    for (int c = 0; c < Cc; ++c) s = fmaf(f[c], w1[c * Hh + k], s);
    dst[b * Hh + k] = s;
}

// ---------------- shared MLP body: layer1 recomputed (no LDS), LN, layer2, LN stats ----------------
__device__ __forceinline__ void mlp_hidden(
    float cx, float cy,
    const float* __restrict__ basev,    // per-batch base (64), wave-uniform
    const float* __restrict__ w1,       // (130,64); rows 128,129 used
    const float* __restrict__ g1, const float* __restrict__ be1,
    const float* __restrict__ w2, const float* __restrict__ b2,
    float acc[Hh], float& mu2o, float& rstd2o)
{
    const float* u = w1 + 128 * Hh;
    const float* v = w1 + 129 * Hh;
    float sum = 0.f, sq = 0.f;
    #pragma unroll
    for (int j = 0; j < Hh; ++j) {
        float t = fmaf(cy, v[j], fmaf(cx, u[j], basev[j]));
        sum += t;
        sq = fmaf(t, t, sq);
    }
    float mu = sum * (1.f / Hh);
    float var = sq * (1.f / Hh) - mu * mu;
    float rstd = rsqrtf(var + 1e-5f);
    #pragma unroll
    for (int i = 0; i < Hh; ++i) acc[i] = 0.f;
    #pragma unroll 4
    for (int j = 0; j < Hh; ++j) {
        float t = fmaf(cy, v[j], fmaf(cx, u[j], basev[j]));   // recompute: 2 FMA, beats LDS latency
        float a = fmaxf(fmaf((t - mu) * rstd, g1[j], be1[j]), 0.f);
        const float* w2r = w2 + j * Hh;
        #pragma unroll
        for (int i = 0; i < Hh; ++i) acc[i] = fmaf(a, w2r[i], acc[i]);
    }
    float sum2 = 0.f, sq2 = 0.f;
    #pragma unroll
    for (int i = 0; i < Hh; ++i) {
        float h = acc[i] + b2[i];
        acc[i] = h;
        sum2 += h;
        sq2 = fmaf(h, h, sq2);
    }
    float mu2 = sum2 * (1.f / Hh);
    float rstd2 = rsqrtf(sq2 * (1.f / Hh) - mu2 * mu2 + 1e-5f);
    mu2o = mu2;
    rstd2o = rstd2;
}

// ---------------- K2: main per-row MLPs (no LDS) ----------------
__global__ __launch_bounds__(128) void k_mlp(
    const float* __restrict__ cand,
    const float* __restrict__ basep, const float* __restrict__ baseo,
    const float* __restrict__ p_w1, const float* __restrict__ p_g1, const float* __restrict__ p_be1,
    const float* __restrict__ p_w2, const float* __restrict__ p_b2,
    const float* __restrict__ p_g2, const float* __restrict__ p_be2,
    const float* __restrict__ p_w3, const float* __restrict__ p_b3,
    const float* __restrict__ o_w1, const float* __restrict__ o_g1, const float* __restrict__ o_be1,
    const float* __restrict__ o_w2, const float* __restrict__ o_b2,
    const float* __restrict__ o_g2, const float* __restrict__ o_be2,
    const float* __restrict__ o_w3, const float* __restrict__ o_b3,
    float* __restrict__ logits, float* __restrict__ offs)
{
    int tid = threadIdx.x;
    int b = blockIdx.x >> 4;            // 16 blocks x 128 threads = 2048 rows per batch
    int n = ((blockIdx.x & 15) << 7) + tid;
    long row = (long)b * Nn + n;
    float cx = cand[row * 2 + 0];
    float cy = cand[row * 2 + 1];
    float acc[Hh];
    float mu2, rstd2;

    // probability MLP -> logit
    mlp_hidden(cx, cy, basep + b * Hh, p_w1, p_g1, p_be1, p_w2, p_b2, acc, mu2, rstd2);
    float lg = p_b3[0];
    #pragma unroll
    for (int i = 0; i < Hh; ++i) {
        float a = fmaxf(fmaf((acc[i] - mu2) * rstd2, p_g2[i], p_be2[i]), 0.f);
        lg = fmaf(a, p_w3[i], lg);
    }
    logits[row] = lg;

    // offset MLP -> (o0, o1)
    mlp_hidden(cx, cy, baseo + b * Hh, o_w1, o_g1, o_be1, o_w2, o_b2, acc, mu2, rstd2);
    float o0 = o_b3[0], o1 = o_b3[1];
    #pragma unroll
    for (int i = 0; i < Hh; ++i) {
        float a = fmaxf(fmaf((acc[i] - mu2) * rstd2, o_g2[i], o_be2[i]), 0.f);
        o0 = fmaf(a, o_w3[i * 2 + 0], o0);
        o1 = fmaf(a, o_w3[i * 2 + 1], o1);
    }
    offs[row * 2 + 0] = o0;
    offs[row * 2 + 1] = o1;
}

// ---------------- K3: fused per-batch softmax + BCE/SL1 partials + top-50 + NMS ----------------
__global__ __launch_bounds__(256) void k_post(
    const float* __restrict__ logits, const float* __restrict__ mask,
    const float* __restrict__ gt, const float* __restrict__ cand,
    const float* __restrict__ offs, const float* __restrict__ off_gt,
    float* __restrict__ out, float* __restrict__ bce_part, float* __restrict__ sl1_part)
{
    __shared__ float vals[Nn];          // p per candidate
    __shared__ float redf[4];
    __shared__ int   redi[4];
    __shared__ float wvv[4]; __shared__ int wvi[4];
    __shared__ int   gidx_sh;
    __shared__ float winv_sh; __shared__ int wini_sh;
    __shared__ int   selidx[Mm];
    __shared__ float tx[Mm], ty[Mm];

    int b = blockIdx.x, tid = threadIdx.x;
    int wave = tid >> 6, lane = tid & 63;
    const float* lg = logits + (long)b * Nn;
    const float* mk = mask + (long)b * Nn;

    // ---- max ----
    float xv[8];
    float mx = -1e30f;
    #pragma unroll
    for (int k = 0; k < 8; ++k) {
        int n = tid + k * 256;
        xv[k] = lg[n] + mk[n];
        mx = fmaxf(mx, xv[k]);
    }
    #pragma unroll
    for (int m = 1; m < 64; m <<= 1) mx = fmaxf(mx, __shfl_xor(mx, m));
    if (lane == 0) redf[wave] = mx;
    __syncthreads();
    float m = fmaxf(fmaxf(redf[0], redf[1]), fmaxf(redf[2], redf[3]));
    __syncthreads();

    // ---- exp + sum ----
    float ev[8]; float es = 0.f;
    #pragma unroll
    for (int k = 0; k < 8; ++k) { ev[k] = expf(xv[k] - m); es += ev[k]; }
    #pragma unroll
    for (int mm = 1; mm < 64; mm <<= 1) es += __shfl_xor(es, mm);
    if (lane == 0) redf[wave] = es;
    __syncthreads();
    float invZ = 1.f / (((redf[0] + redf[1]) + redf[2]) + redf[3]);

    // ---- p, BCE partial, gt index ----
    const float* g = gt + (long)b * Nn;
    float bs = 0.f;
    #pragma unroll
    for (int k = 0; k < 8; ++k) {
        int n = tid + k * 256;
        float pv = ev[k] * invZ;
        vals[n] = pv;
        float gv = g[n];
        float lp = fmaxf(logf(pv), -100.f);
        float l1p = fmaxf(log1pf(-pv), -100.f);
        bs += gv * lp + (1.f - gv) * l1p;
        if (gv > 0.5f) gidx_sh = n;     // one-hot: exactly one writer
    }
    #pragma unroll
    for (int mm = 1; mm < 64; mm <<= 1) bs += __shfl_xor(bs, mm);
    if (lane == 0) redf[wave] = bs;
    __syncthreads();
    if (tid == 0) {
        bce_part[b] = ((redf[0] + redf[1]) + redf[2]) + redf[3];
        int gi = gidx_sh;
        float s1 = 0.f;
        #pragma unroll
        for (int c = 0; c < 2; ++c) {
            float d = offs[((long)b * Nn + gi) * 2 + c] - off_gt[b * 2 + c];
            float ad = fabsf(d);
            s1 += (ad < 1.f) ? 0.5f * d * d : ad - 0.5f;
        }
        sl1_part[b] = s1;
    }
    __syncthreads();

    // ---- top-50 (exact lax.top_k order: desc value, asc index on ties) ----
    float bv = -1.f; int bi = 0x7fffffff;
    #pragma unroll
    for (int k = 0; k < 8; ++k) {
        int n = tid + k * 256;          // ascending -> min idx kept on ties
        float v = vals[n];
        if (v > bv) { bv = v; bi = n; }
    }
    for (int it = 0; it < Mm; ++it) {
        float rv = bv; int ri = bi;
        #pragma unroll
        for (int mm = 1; mm < 64; mm <<= 1) {
            float v2 = __shfl_xor(rv, mm); int i2 = __shfl_xor(ri, mm);
            if (v2 > rv || (v2 == rv && i2 < ri)) { rv = v2; ri = i2; }
        }
        if (lane == 0) { wvv[wave] = rv; wvi[wave] = ri; }
        __syncthreads();
        if (tid == 0) {
            float wv = wvv[0]; int wi = wvi[0];
            #pragma unroll
            for (int k = 1; k < 4; ++k) {
                if (wvv[k] > wv || (wvv[k] == wv && wvi[k] < wi)) { wv = wvv[k]; wi = wvi[k]; }
            }
            wini_sh = wi;
            selidx[it] = wi;
        }
        __syncthreads();
        int wi = wini_sh;
        if ((wi & 255) == tid) {        // owner: remove + rescan local 8
            vals[wi] = -1.f;
            bv = -1.f; bi = 0x7fffffff;
            #pragma unroll
            for (int k = 0; k < 8; ++k) {
                int n = tid + k * 256;
                float v = vals[n];
                if (v > bv) { bv = v; bi = n; }
            }
        }
        __syncthreads();
    }

    // ---- gather + NMS ----
    if (tid < Mm) {
        int idx = selidx[tid];
        long r = (long)b * Nn + idx;
        tx[tid] = cand[r * 2 + 0] + offs[r * 2 + 0];
        ty[tid] = cand[r * 2 + 1] + offs[r * 2 + 1];
    }
    __syncthreads();
    if (tid == 0) {
        float sx[6], sy[6];
        #pragma unroll
        for (int k = 0; k < 6; ++k) { sx[k] = tx[k]; sy[k] = ty[k]; }
        int cnt = 1;
        for (int i = 1; i < Mm; ++i) {
            bool close = false;
            #pragma unroll
            for (int k = 0; k < 6; ++k) {
                float dx = sx[k] - tx[i], dy = sy[k] - ty[i];
                close = close || ((k < cnt) && (dx * dx + dy * dy < 2.0f));
            }
            if (!close && cnt < 6) { sx[cnt] = tx[i]; sy[cnt] = ty[i]; cnt++; }
        }
        #pragma unroll
        for (int k = 0; k < 6; ++k) {
            out[(b * 6 + k) * 2 + 0] = sx[k];
            out[(b * 6 + k) * 2 + 1] = sy[k];
        }
    }
}

// ---------------- K4: final loss ----------------
__global__ void k_loss(const float* __restrict__ bce_part, const float* __restrict__ sl1_part,
                       float* __restrict__ out) {
    if (threadIdx.x == 0 && blockIdx.x == 0) {
        float sb = 0.f, ss = 0.f;
        for (int b = 0; b < Bb; ++b) { sb += bce_part[b]; ss += sl1_part[b]; }
        out[0] = -sb / (float)(Bb * Nn) + ss / (float)(Bb * 2);
    }
}

extern "C" void kernel_launch(void* const* d_in, const int* in_sizes, int n_in,
                              void* d_out, int out_size, void* d_ws, size_t ws_size,
                              hipStream_t stream) {
    const float* feat  = (const float*)d_in[0];
    const float* cand  = (const float*)d_in[1];
    const float* mask  = (const float*)d_in[2];
    const float* gt    = (const float*)d_in[3];
    const float* ogt   = (const float*)d_in[4];
    const float* p_w1  = (const float*)d_in[5];
    const float* p_b1  = (const float*)d_in[6];
    const float* p_g1  = (const float*)d_in[7];
    const float* p_be1 = (const float*)d_in[8];
    const float* p_w2  = (const float*)d_in[9];
    const float* p_b2  = (const float*)d_in[10];
    const float* p_g2  = (const float*)d_in[11];
    const float* p_be2 = (const float*)d_in[12];
    const float* p_w3  = (const float*)d_in[13];
    const float* p_b3  = (const float*)d_in[14];
    const float* o_w1  = (const float*)d_in[15];
    const float* o_b1  = (const float*)d_in[16];
    const float* o_g1  = (const float*)d_in[17];
    const float* o_be1 = (const float*)d_in[18];
    const float* o_w2  = (const float*)d_in[19];
    const float* o_g2  = (const float*)d_in[20];   // NOTE: dict order puts o_g2 before o_b2
    const float* o_b2  = (const float*)d_in[21];
    const float* o_be2 = (const float*)d_in[22];
    const float* o_w3  = (const float*)d_in[23];
    const float* o_b3  = (const float*)d_in[24];

    float* ws       = (float*)d_ws;
    float* basep    = ws;                       // B*H
    float* baseo    = basep + Bb * Hh;          // B*H
    float* logits   = baseo + Bb * Hh;          // B*N
    float* offs     = logits + Bb * Nn;         // B*N*2
    float* bce_part = offs + (long)Bb * Nn * 2; // B
    float* sl1_part = bce_part + Bb;            // B

    float* out = (float*)d_out;                 // (B,6,2) floats then loss scalar

    k_base<<<Bb, 128, 0, stream>>>(feat, p_w1, p_b1, o_w1, o_b1, basep, baseo);
    k_mlp<<<Bb * 16, 128, 0, stream>>>(cand, basep, baseo,
        p_w1, p_g1, p_be1, p_w2, p_b2, p_g2, p_be2, p_w3, p_b3,
        o_w1, o_g1, o_be1, o_w2, o_b2, o_g2, o_be2, o_w3, o_b3,
        logits, offs);
    k_post<<<Bb, 256, 0, stream>>>(logits, mask, gt, cand, offs, ogt, out, bce_part, sl1_part);
    k_loss<<<1, 1, 0, stream>>>(bce_part, sl1_part, out + Bb * 6 * 2);
}

// Round 3
// 177.161 us; speedup vs baseline: 1.4848x; 1.0943x over previous
//
#include <hip/hip_runtime.h>
#include <hip/hip_bf16.h>
#include <math.h>

#define Bb 256
#define Nn 2048
#define Cc 128
#define Hh 64
#define Mm 50

// ---------------- K1: per-batch feat @ W1[:128] + b1 for BOTH MLPs ----------------
__global__ __launch_bounds__(128) void k_base(const float* __restrict__ feat,
                                              const float* __restrict__ p_w1,
                                              const float* __restrict__ p_b1,
                                              const float* __restrict__ o_w1,
                                              const float* __restrict__ o_b1,
                                              float* __restrict__ basep,
                                              float* __restrict__ baseo) {
    int b = blockIdx.x, tid = threadIdx.x;
    int k = tid & 63;
    bool lo = tid < 64;                     // wave-uniform select
    const float* w1 = lo ? p_w1 : o_w1;
    const float* b1 = lo ? p_b1 : o_b1;
    float* dst = lo ? basep : baseo;
    const float* f = feat + b * Cc;
    float s = b1[k];
    #pragma unroll 8
    for (int c = 0; c < Cc; ++c) s = fmaf(f[c], w1[c * Hh + k], s);
    dst[b * Hh + k] = s;
}

// ---------------- K2: prob MLP for all rows (a[] stored in regs once) ----------------
__global__ __launch_bounds__(256) void k_mlp_p(
    const float* __restrict__ cand, const float* __restrict__ basep,
    const float* __restrict__ p_w1, const float* __restrict__ p_g1, const float* __restrict__ p_be1,
    const float* __restrict__ p_w2, const float* __restrict__ p_b2,
    const float* __restrict__ p_g2, const float* __restrict__ p_be2,
    const float* __restrict__ p_w3, const float* __restrict__ p_b3,
    float* __restrict__ logits)
{
    int tid = threadIdx.x;
    int b = blockIdx.x >> 3;            // 8 blocks x 256 threads = 2048 rows per batch
    int n = ((blockIdx.x & 7) << 8) + tid;
    long row = (long)b * Nn + n;
    float cx = cand[row * 2 + 0];
    float cy = cand[row * 2 + 1];
    const float* basev = basep + b * Hh;
    const float* u = p_w1 + 128 * Hh;
    const float* v = p_w1 + 129 * Hh;

    // layer 1 + LN + ReLU, a[] lives in registers
    float a[Hh];
    float sum = 0.f, sq = 0.f;
    #pragma unroll
    for (int j = 0; j < Hh; ++j) {
        float t = fmaf(cy, v[j], fmaf(cx, u[j], basev[j]));
        a[j] = t;
        sum += t;
        sq = fmaf(t, t, sq);
    }
    float mu = sum * (1.f / Hh);
    float rstd = rsqrtf(sq * (1.f / Hh) - mu * mu + 1e-5f);
    #pragma unroll
    for (int j = 0; j < Hh; ++j)
        a[j] = fmaxf(fmaf((a[j] - mu) * rstd, p_g1[j], p_be1[j]), 0.f);

    // layer 2
    float h[Hh];
    #pragma unroll
    for (int i = 0; i < Hh; ++i) h[i] = 0.f;
    #pragma unroll 4
    for (int j = 0; j < Hh; ++j) {
        float av = a[j];
        const float* w2r = p_w2 + j * Hh;
        #pragma unroll
        for (int i = 0; i < Hh; ++i) h[i] = fmaf(av, w2r[i], h[i]);
    }
    float sum2 = 0.f, sq2 = 0.f;
    #pragma unroll
    for (int i = 0; i < Hh; ++i) {
        float hv = h[i] + p_b2[i];
        h[i] = hv;
        sum2 += hv;
        sq2 = fmaf(hv, hv, sq2);
    }
    float mu2 = sum2 * (1.f / Hh);
    float rstd2 = rsqrtf(sq2 * (1.f / Hh) - mu2 * mu2 + 1e-5f);

    // head
    float lg = p_b3[0];
    #pragma unroll
    for (int i = 0; i < Hh; ++i) {
        float aa = fmaxf(fmaf((h[i] - mu2) * rstd2, p_g2[i], p_be2[i]), 0.f);
        lg = fmaf(aa, p_w3[i], lg);
    }
    logits[row] = lg;
}

// ---------------- K3: fused per-batch softmax + BCE partial + top-50 ----------------
__global__ __launch_bounds__(256) void k_post(
    const float* __restrict__ logits, const float* __restrict__ mask,
    const float* __restrict__ gt,
    float* __restrict__ bce_part, int* __restrict__ selidx_g, int* __restrict__ gidx_g)
{
    __shared__ float vals[Nn];          // p per candidate
    __shared__ float redf[4];
    __shared__ float wvv[4]; __shared__ int wvi[4];
    __shared__ int   gidx_sh;
    __shared__ int   wini_sh;
    __shared__ int   selidx[Mm];

    int b = blockIdx.x, tid = threadIdx.x;
    int wave = tid >> 6, lane = tid & 63;
    const float* lg = logits + (long)b * Nn;
    const float* mk = mask + (long)b * Nn;

    // ---- max ----
    float xv[8];
    float mx = -1e30f;
    #pragma unroll
    for (int k = 0; k < 8; ++k) {
        int n = tid + k * 256;
        xv[k] = lg[n] + mk[n];
        mx = fmaxf(mx, xv[k]);
    }
    #pragma unroll
    for (int m = 1; m < 64; m <<= 1) mx = fmaxf(mx, __shfl_xor(mx, m));
    if (lane == 0) redf[wave] = mx;
    __syncthreads();
    float m = fmaxf(fmaxf(redf[0], redf[1]), fmaxf(redf[2], redf[3]));
    __syncthreads();

    // ---- exp + sum ----
    float ev[8]; float es = 0.f;
    #pragma unroll
    for (int k = 0; k < 8; ++k) { ev[k] = expf(xv[k] - m); es += ev[k]; }
    #pragma unroll
    for (int mm = 1; mm < 64; mm <<= 1) es += __shfl_xor(es, mm);
    if (lane == 0) redf[wave] = es;
    __syncthreads();
    float invZ = 1.f / (((redf[0] + redf[1]) + redf[2]) + redf[3]);

    // ---- p, BCE partial, gt index ----
    const float* g = gt + (long)b * Nn;
    float bs = 0.f;
    #pragma unroll
    for (int k = 0; k < 8; ++k) {
        int n = tid + k * 256;
        float pv = ev[k] * invZ;
        vals[n] = pv;
        float gv = g[n];
        float lp = fmaxf(logf(pv), -100.f);
        float l1p = fmaxf(log1pf(-pv), -100.f);
        bs += gv * lp + (1.f - gv) * l1p;
        if (gv > 0.5f) gidx_sh = n;     // one-hot: exactly one writer
    }
    #pragma unroll
    for (int mm = 1; mm < 64; mm <<= 1) bs += __shfl_xor(bs, mm);
    if (lane == 0) redf[wave] = bs;
    __syncthreads();
    if (tid == 0) {
        bce_part[b] = ((redf[0] + redf[1]) + redf[2]) + redf[3];
        gidx_g[b] = gidx_sh;
    }

    // ---- top-50 (exact lax.top_k order: desc value, asc index on ties) ----
    float bv = -1.f; int bi = 0x7fffffff;
    #pragma unroll
    for (int k = 0; k < 8; ++k) {
        int n = tid + k * 256;          // ascending -> min idx kept on ties
        float v = vals[n];
        if (v > bv) { bv = v; bi = n; }
    }
    for (int it = 0; it < Mm; ++it) {
        float rv = bv; int ri = bi;
        #pragma unroll
        for (int mm = 1; mm < 64; mm <<= 1) {
            float v2 = __shfl_xor(rv, mm); int i2 = __shfl_xor(ri, mm);
            if (v2 > rv || (v2 == rv && i2 < ri)) { rv = v2; ri = i2; }
        }
        if (lane == 0) { wvv[wave] = rv; wvi[wave] = ri; }
        __syncthreads();
        if (tid == 0) {
            float wv = wvv[0]; int wi = wvi[0];
            #pragma unroll
            for (int k = 1; k < 4; ++k) {
                if (wvv[k] > wv || (wvv[k] == wv && wvi[k] < wi)) { wv = wvv[k]; wi = wvi[k]; }
            }
            wini_sh = wi;
            selidx[it] = wi;
        }
        __syncthreads();
        int wi = wini_sh;
        if ((wi & 255) == tid) {        // owner: remove + rescan local 8
            vals[wi] = -1.f;
            bv = -1.f; bi = 0x7fffffff;
            #pragma unroll
            for (int k = 0; k < 8; ++k) {
                int n = tid + k * 256;
                float v = vals[n];
                if (v > bv) { bv = v; bi = n; }
            }
        }
        __syncthreads();
    }
    if (tid < Mm) selidx_g[b * Mm + tid] = selidx[tid];
}

// ---------------- offset MLP for one row (same math as R1, bit-identical) ----------------
__device__ __forceinline__ void off_mlp_row(
    long row, const float* __restrict__ cand, const float* __restrict__ basev,
    const float* __restrict__ o_w1, const float* __restrict__ o_g1, const float* __restrict__ o_be1,
    const float* __restrict__ o_w2, const float* __restrict__ o_b2,
    const float* __restrict__ o_g2, const float* __restrict__ o_be2,
    const float* __restrict__ o_w3, const float* __restrict__ o_b3,
    float& o0, float& o1)
{
    float cx = cand[row * 2 + 0];
    float cy = cand[row * 2 + 1];
    const float* u = o_w1 + 128 * Hh;
    const float* v = o_w1 + 129 * Hh;
    float a[Hh];
    float sum = 0.f, sq = 0.f;
    #pragma unroll
    for (int j = 0; j < Hh; ++j) {
        float t = fmaf(cy, v[j], fmaf(cx, u[j], basev[j]));
        a[j] = t;
        sum += t;
        sq = fmaf(t, t, sq);
    }
    float mu = sum * (1.f / Hh);
    float rstd = rsqrtf(sq * (1.f / Hh) - mu * mu + 1e-5f);
    #pragma unroll
    for (int j = 0; j < Hh; ++j)
        a[j] = fmaxf(fmaf((a[j] - mu) * rstd, o_g1[j], o_be1[j]), 0.f);
    float h[Hh];
    #pragma unroll
    for (int i = 0; i < Hh; ++i) h[i] = 0.f;
    #pragma unroll 4
    for (int j = 0; j < Hh; ++j) {
        float av = a[j];
        const float* w2r = o_w2 + j * Hh;
        #pragma unroll
        for (int i = 0; i < Hh; ++i) h[i] = fmaf(av, w2r[i], h[i]);
    }
    float sum2 = 0.f, sq2 = 0.f;
    #pragma unroll
    for (int i = 0; i < Hh; ++i) {
        float hv = h[i] + o_b2[i];
        h[i] = hv;
        sum2 += hv;
        sq2 = fmaf(hv, hv, sq2);
    }
    float mu2 = sum2 * (1.f / Hh);
    float rstd2 = rsqrtf(sq2 * (1.f / Hh) - mu2 * mu2 + 1e-5f);
    o0 = o_b3[0]; o1 = o_b3[1];
    #pragma unroll
    for (int i = 0; i < Hh; ++i) {
        float aa = fmaxf(fmaf((h[i] - mu2) * rstd2, o_g2[i], o_be2[i]), 0.f);
        o0 = fmaf(aa, o_w3[i * 2 + 0], o0);
        o1 = fmaf(aa, o_w3[i * 2 + 1], o1);
    }
}

// ---------------- K4: offset MLP on 51 rows/batch + gather + NMS + SL1 ----------------
__global__ __launch_bounds__(64) void k_off(
    const float* __restrict__ cand, const float* __restrict__ baseo,
    const int* __restrict__ selidx_g, const int* __restrict__ gidx_g,
    const float* __restrict__ off_gt,
    const float* __restrict__ o_w1, const float* __restrict__ o_g1, const float* __restrict__ o_be1,
    const float* __restrict__ o_w2, const float* __restrict__ o_b2,
    const float* __restrict__ o_g2, const float* __restrict__ o_be2,
    const float* __restrict__ o_w3, const float* __restrict__ o_b3,
    float* __restrict__ out, float* __restrict__ sl1_part)
{
    __shared__ float tx[Mm], ty[Mm];
    int b = blockIdx.x, tid = threadIdx.x;
    const float* basev = baseo + b * Hh;

    int idx;
    if (tid < Mm)        idx = selidx_g[b * Mm + tid];
    else if (tid == Mm)  idx = gidx_g[b];
    else                 idx = 0;
    long row = (long)b * Nn + idx;

    float o0, o1;
    off_mlp_row(row, cand, basev, o_w1, o_g1, o_be1, o_w2, o_b2, o_g2, o_be2, o_w3, o_b3, o0, o1);

    if (tid < Mm) {
        tx[tid] = cand[row * 2 + 0] + o0;
        ty[tid] = cand[row * 2 + 1] + o1;
    } else if (tid == Mm) {
        float s1 = 0.f;
        float d0 = o0 - off_gt[b * 2 + 0];
        float ad0 = fabsf(d0);
        s1 += (ad0 < 1.f) ? 0.5f * d0 * d0 : ad0 - 0.5f;
        float d1 = o1 - off_gt[b * 2 + 1];
        float ad1 = fabsf(d1);
        s1 += (ad1 < 1.f) ? 0.5f * d1 * d1 : ad1 - 0.5f;
        sl1_part[b] = s1;
    }
    __syncthreads();
    if (tid == 0) {
        float sx[6], sy[6];
        #pragma unroll
        for (int k = 0; k < 6; ++k) { sx[k] = tx[k]; sy[k] = ty[k]; }
        int cnt = 1;
        for (int i = 1; i < Mm; ++i) {
            bool close = false;
            #pragma unroll
            for (int k = 0; k < 6; ++k) {
                float dx = sx[k] - tx[i], dy = sy[k] - ty[i];
                close = close || ((k < cnt) && (dx * dx + dy * dy < 2.0f));
            }
            if (!close && cnt < 6) { sx[cnt] = tx[i]; sy[cnt] = ty[i]; cnt++; }
        }
        #pragma unroll
        for (int k = 0; k < 6; ++k) {
            out[(b * 6 + k) * 2 + 0] = sx[k];
            out[(b * 6 + k) * 2 + 1] = sy[k];
        }
    }
}

// ---------------- K5: final loss (parallel) ----------------
__global__ __launch_bounds__(256) void k_loss(const float* __restrict__ bce_part,
                                              const float* __restrict__ sl1_part,
                                              float* __restrict__ out) {
    __shared__ float redb[4], reds[4];
    int tid = threadIdx.x, wave = tid >> 6, lane = tid & 63;
    float sb = bce_part[tid];
    float ss = sl1_part[tid];
    #pragma unroll
    for (int mm = 1; mm < 64; mm <<= 1) { sb += __shfl_xor(sb, mm); ss += __shfl_xor(ss, mm); }
    if (lane == 0) { redb[wave] = sb; reds[wave] = ss; }
    __syncthreads();
    if (tid == 0) {
        float tb = ((redb[0] + redb[1]) + redb[2]) + redb[3];
        float ts = ((reds[0] + reds[1]) + reds[2]) + reds[3];
        out[0] = -tb / (float)(Bb * Nn) + ts / (float)(Bb * 2);
    }
}

extern "C" void kernel_launch(void* const* d_in, const int* in_sizes, int n_in,
                              void* d_out, int out_size, void* d_ws, size_t ws_size,
                              hipStream_t stream) {
    const float* feat  = (const float*)d_in[0];
    const float* cand  = (const float*)d_in[1];
    const float* mask  = (const float*)d_in[2];
    const float* gt    = (const float*)d_in[3];
    const float* ogt   = (const float*)d_in[4];
    const float* p_w1  = (const float*)d_in[5];
    const float* p_b1  = (const float*)d_in[6];
    const float* p_g1  = (const float*)d_in[7];
    const float* p_be1 = (const float*)d_in[8];
    const float* p_w2  = (const float*)d_in[9];
    const float* p_b2  = (const float*)d_in[10];
    const float* p_g2  = (const float*)d_in[11];
    const float* p_be2 = (const float*)d_in[12];
    const float* p_w3  = (const float*)d_in[13];
    const float* p_b3  = (const float*)d_in[14];
    const float* o_w1  = (const float*)d_in[15];
    const float* o_b1  = (const float*)d_in[16];
    const float* o_g1  = (const float*)d_in[17];
    const float* o_be1 = (const float*)d_in[18];
    const float* o_w2  = (const float*)d_in[19];
    const float* o_g2  = (const float*)d_in[20];   // NOTE: dict order puts o_g2 before o_b2
    const float* o_b2  = (const float*)d_in[21];
    const float* o_be2 = (const float*)d_in[22];
    const float* o_w3  = (const float*)d_in[23];
    const float* o_b3  = (const float*)d_in[24];

    float* ws       = (float*)d_ws;
    float* basep    = ws;                        // B*H
    float* baseo    = basep + Bb * Hh;           // B*H
    float* logits   = baseo + Bb * Hh;           // B*N
    float* bce_part = logits + (long)Bb * Nn;    // B
    float* sl1_part = bce_part + Bb;             // B
    int*   selidx_g = (int*)(sl1_part + Bb);     // B*M ints
    int*   gidx_g   = selidx_g + Bb * Mm;        // B ints

    float* out = (float*)d_out;                  // (B,6,2) floats then loss scalar

    k_base<<<Bb, 128, 0, stream>>>(feat, p_w1, p_b1, o_w1, o_b1, basep, baseo);
    k_mlp_p<<<Bb * 8, 256, 0, stream>>>(cand, basep,
        p_w1, p_g1, p_be1, p_w2, p_b2, p_g2, p_be2, p_w3, p_b3, logits);
    k_post<<<Bb, 256, 0, stream>>>(logits, mask, gt, bce_part, selidx_g, gidx_g);
    k_off<<<Bb, 64, 0, stream>>>(cand, baseo, selidx_g, gidx_g, ogt,
        o_w1, o_g1, o_be1, o_w2, o_b2, o_g2, o_be2, o_w3, o_b3, out, sl1_part);
    k_loss<<<1, 256, 0, stream>>>(bce_part, sl1_part, out + Bb * 6 * 2);
}

// Round 4
// 176.507 us; speedup vs baseline: 1.4903x; 1.0037x over previous
//
#include <hip/hip_runtime.h>
#include <hip/hip_bf16.h>
#include <math.h>

#define Bb 256
#define Nn 2048
#define Cc 128
#define Hh 64
#define Mm 50

// ---------------- K1: per-batch feat @ W1[:128] + b1 for BOTH MLPs ----------------
__global__ __launch_bounds__(128) void k_base(const float* __restrict__ feat,
                                              const float* __restrict__ p_w1,
                                              const float* __restrict__ p_b1,
                                              const float* __restrict__ o_w1,
                                              const float* __restrict__ o_b1,
                                              float* __restrict__ basep,
                                              float* __restrict__ baseo) {
    int b = blockIdx.x, tid = threadIdx.x;
    int k = tid & 63;
    bool lo = tid < 64;                     // wave-uniform select
    const float* w1 = lo ? p_w1 : o_w1;
    const float* b1 = lo ? p_b1 : o_b1;
    float* dst = lo ? basep : baseo;
    const float* f = feat + b * Cc;
    float s = b1[k];
    #pragma unroll 8
    for (int c = 0; c < Cc; ++c) s = fmaf(f[c], w1[c * Hh + k], s);
    dst[b * Hh + k] = s;
}

// ---------------- K2: prob MLP for all rows (regs freed via min-waves=1) ----------------
__global__ __launch_bounds__(256, 1) void k_mlp_p(
    const float* __restrict__ cand, const float* __restrict__ basep,
    const float* __restrict__ p_w1, const float* __restrict__ p_g1, const float* __restrict__ p_be1,
    const float* __restrict__ p_w2, const float* __restrict__ p_b2,
    const float* __restrict__ p_g2, const float* __restrict__ p_be2,
    const float* __restrict__ p_w3, const float* __restrict__ p_b3,
    float* __restrict__ logits)
{
    int tid = threadIdx.x;
    int b = blockIdx.x >> 3;            // 8 blocks x 256 threads = 2048 rows per batch
    int n = ((blockIdx.x & 7) << 8) + tid;
    long row = (long)b * Nn + n;
    float cx = cand[row * 2 + 0];
    float cy = cand[row * 2 + 1];
    const float* basev = basep + b * Hh;
    const float* u = p_w1 + 128 * Hh;
    const float* v = p_w1 + 129 * Hh;

    // layer 1 + LN + ReLU, a[] lives in registers
    float a[Hh];
    float sum = 0.f, sq = 0.f;
    #pragma unroll
    for (int j = 0; j < Hh; ++j) {
        float t = fmaf(cy, v[j], fmaf(cx, u[j], basev[j]));
        a[j] = t;
        sum += t;
        sq = fmaf(t, t, sq);
    }
    float mu = sum * (1.f / Hh);
    float rstd = rsqrtf(sq * (1.f / Hh) - mu * mu + 1e-5f);
    #pragma unroll
    for (int j = 0; j < Hh; ++j)
        a[j] = fmaxf(fmaf((a[j] - mu) * rstd, p_g1[j], p_be1[j]), 0.f);

    // layer 2
    float h[Hh];
    #pragma unroll
    for (int i = 0; i < Hh; ++i) h[i] = 0.f;
    #pragma unroll 4
    for (int j = 0; j < Hh; ++j) {
        float av = a[j];
        const float* w2r = p_w2 + j * Hh;
        #pragma unroll
        for (int i = 0; i < Hh; ++i) h[i] = fmaf(av, w2r[i], h[i]);
    }
    float sum2 = 0.f, sq2 = 0.f;
    #pragma unroll
    for (int i = 0; i < Hh; ++i) {
        float hv = h[i] + p_b2[i];
        h[i] = hv;
        sum2 += hv;
        sq2 = fmaf(hv, hv, sq2);
    }
    float mu2 = sum2 * (1.f / Hh);
    float rstd2 = rsqrtf(sq2 * (1.f / Hh) - mu2 * mu2 + 1e-5f);

    // head
    float lg = p_b3[0];
    #pragma unroll
    for (int i = 0; i < Hh; ++i) {
        float aa = fmaxf(fmaf((h[i] - mu2) * rstd2, p_g2[i], p_be2[i]), 0.f);
        lg = fmaf(aa, p_w3[i], lg);
    }
    logits[row] = lg;
}

// ---------------- K3: fused per-batch softmax + BCE partial + top-50 ----------------
__global__ __launch_bounds__(256) void k_post(
    const float* __restrict__ logits, const float* __restrict__ mask,
    const float* __restrict__ gt,
    float* __restrict__ bce_part, int* __restrict__ selidx_g, int* __restrict__ gidx_g)
{
    __shared__ float vals[Nn];          // p per candidate
    __shared__ float redf[4];
    __shared__ float wvv[4]; __shared__ int wvi[4];
    __shared__ int   gidx_sh;
    __shared__ int   wini_sh;
    __shared__ int   selidx[Mm];

    int b = blockIdx.x, tid = threadIdx.x;
    int wave = tid >> 6, lane = tid & 63;
    const float* lg = logits + (long)b * Nn;
    const float* mk = mask + (long)b * Nn;

    // ---- max ----
    float xv[8];
    float mx = -1e30f;
    #pragma unroll
    for (int k = 0; k < 8; ++k) {
        int n = tid + k * 256;
        xv[k] = lg[n] + mk[n];
        mx = fmaxf(mx, xv[k]);
    }
    #pragma unroll
    for (int m = 1; m < 64; m <<= 1) mx = fmaxf(mx, __shfl_xor(mx, m));
    if (lane == 0) redf[wave] = mx;
    __syncthreads();
    float m = fmaxf(fmaxf(redf[0], redf[1]), fmaxf(redf[2], redf[3]));
    __syncthreads();

    // ---- exp + sum ----
    float ev[8]; float es = 0.f;
    #pragma unroll
    for (int k = 0; k < 8; ++k) { ev[k] = expf(xv[k] - m); es += ev[k]; }
    #pragma unroll
    for (int mm = 1; mm < 64; mm <<= 1) es += __shfl_xor(es, mm);
    if (lane == 0) redf[wave] = es;
    __syncthreads();
    float invZ = 1.f / (((redf[0] + redf[1]) + redf[2]) + redf[3]);

    // ---- p, BCE partial, gt index ----
    const float* g = gt + (long)b * Nn;
    float bs = 0.f;
    #pragma unroll
    for (int k = 0; k < 8; ++k) {
        int n = tid + k * 256;
        float pv = ev[k] * invZ;
        vals[n] = pv;
        float gv = g[n];
        float lp = fmaxf(logf(pv), -100.f);
        float l1p = fmaxf(log1pf(-pv), -100.f);
        bs += gv * lp + (1.f - gv) * l1p;
        if (gv > 0.5f) gidx_sh = n;     // one-hot: exactly one writer
    }
    #pragma unroll
    for (int mm = 1; mm < 64; mm <<= 1) bs += __shfl_xor(bs, mm);
    if (lane == 0) redf[wave] = bs;
    __syncthreads();
    if (tid == 0) {
        bce_part[b] = ((redf[0] + redf[1]) + redf[2]) + redf[3];
        gidx_g[b] = gidx_sh;
    }

    // ---- top-50 (exact lax.top_k order: desc value, asc index on ties) ----
    float bv = -1.f; int bi = 0x7fffffff;
    #pragma unroll
    for (int k = 0; k < 8; ++k) {
        int n = tid + k * 256;          // ascending -> min idx kept on ties
        float v = vals[n];
        if (v > bv) { bv = v; bi = n; }
    }
    for (int it = 0; it < Mm; ++it) {
        float rv = bv; int ri = bi;
        #pragma unroll
        for (int mm = 1; mm < 64; mm <<= 1) {
            float v2 = __shfl_xor(rv, mm); int i2 = __shfl_xor(ri, mm);
            if (v2 > rv || (v2 == rv && i2 < ri)) { rv = v2; ri = i2; }
        }
        if (lane == 0) { wvv[wave] = rv; wvi[wave] = ri; }
        __syncthreads();
        if (tid == 0) {
            float wv = wvv[0]; int wi = wvi[0];
            #pragma unroll
            for (int k = 1; k < 4; ++k) {
                if (wvv[k] > wv || (wvv[k] == wv && wvi[k] < wi)) { wv = wvv[k]; wi = wvi[k]; }
            }
            wini_sh = wi;
            selidx[it] = wi;
        }
        __syncthreads();
        int wi = wini_sh;
        if ((wi & 255) == tid) {        // owner: remove + rescan local 8
            vals[wi] = -1.f;
            bv = -1.f; bi = 0x7fffffff;
            #pragma unroll
            for (int k = 0; k < 8; ++k) {
                int n = tid + k * 256;
                float v = vals[n];
                if (v > bv) { bv = v; bi = n; }
            }
        }
        __syncthreads();
    }
    if (tid < Mm) selidx_g[b * Mm + tid] = selidx[tid];
}

// ---------------- offset MLP for one row (same math as R1, bit-identical) ----------------
__device__ __forceinline__ void off_mlp_row(
    long row, const float* __restrict__ cand, const float* __restrict__ basev,
    const float* __restrict__ o_w1, const float* __restrict__ o_g1, const float* __restrict__ o_be1,
    const float* __restrict__ o_w2, const float* __restrict__ o_b2,
    const float* __restrict__ o_g2, const float* __restrict__ o_be2,
    const float* __restrict__ o_w3, const float* __restrict__ o_b3,
    float& o0, float& o1)
{
    float cx = cand[row * 2 + 0];
    float cy = cand[row * 2 + 1];
    const float* u = o_w1 + 128 * Hh;
    const float* v = o_w1 + 129 * Hh;
    float a[Hh];
    float sum = 0.f, sq = 0.f;
    #pragma unroll
    for (int j = 0; j < Hh; ++j) {
        float t = fmaf(cy, v[j], fmaf(cx, u[j], basev[j]));
        a[j] = t;
        sum += t;
        sq = fmaf(t, t, sq);
    }
    float mu = sum * (1.f / Hh);
    float rstd = rsqrtf(sq * (1.f / Hh) - mu * mu + 1e-5f);
    #pragma unroll
    for (int j = 0; j < Hh; ++j)
        a[j] = fmaxf(fmaf((a[j] - mu) * rstd, o_g1[j], o_be1[j]), 0.f);
    float h[Hh];
    #pragma unroll
    for (int i = 0; i < Hh; ++i) h[i] = 0.f;
    #pragma unroll 4
    for (int j = 0; j < Hh; ++j) {
        float av = a[j];
        const float* w2r = o_w2 + j * Hh;
        #pragma unroll
        for (int i = 0; i < Hh; ++i) h[i] = fmaf(av, w2r[i], h[i]);
    }
    float sum2 = 0.f, sq2 = 0.f;
    #pragma unroll
    for (int i = 0; i < Hh; ++i) {
        float hv = h[i] + o_b2[i];
        h[i] = hv;
        sum2 += hv;
        sq2 = fmaf(hv, hv, sq2);
    }
    float mu2 = sum2 * (1.f / Hh);
    float rstd2 = rsqrtf(sq2 * (1.f / Hh) - mu2 * mu2 + 1e-5f);
    o0 = o_b3[0]; o1 = o_b3[1];
    #pragma unroll
    for (int i = 0; i < Hh; ++i) {
        float aa = fmaxf(fmaf((h[i] - mu2) * rstd2, o_g2[i], o_be2[i]), 0.f);
        o0 = fmaf(aa, o_w3[i * 2 + 0], o0);
        o1 = fmaf(aa, o_w3[i * 2 + 1], o1);
    }
}

// ---------------- K4: offset MLP on 51 rows/batch + gather + NMS + SL1 ----------------
__global__ __launch_bounds__(64, 1) void k_off(
    const float* __restrict__ cand, const float* __restrict__ baseo,
    const int* __restrict__ selidx_g, const int* __restrict__ gidx_g,
    const float* __restrict__ off_gt,
    const float* __restrict__ o_w1, const float* __restrict__ o_g1, const float* __restrict__ o_be1,
    const float* __restrict__ o_w2, const float* __restrict__ o_b2,
    const float* __restrict__ o_g2, const float* __restrict__ o_be2,
    const float* __restrict__ o_w3, const float* __restrict__ o_b3,
    float* __restrict__ out, float* __restrict__ sl1_part)
{
    __shared__ float tx[Mm], ty[Mm];
    int b = blockIdx.x, tid = threadIdx.x;
    const float* basev = baseo + b * Hh;

    int idx;
    if (tid < Mm)        idx = selidx_g[b * Mm + tid];
    else if (tid == Mm)  idx = gidx_g[b];
    else                 idx = 0;
    long row = (long)b * Nn + idx;

    float o0, o1;
    off_mlp_row(row, cand, basev, o_w1, o_g1, o_be1, o_w2, o_b2, o_g2, o_be2, o_w3, o_b3, o0, o1);

    if (tid < Mm) {
        tx[tid] = cand[row * 2 + 0] + o0;
        ty[tid] = cand[row * 2 + 1] + o1;
    } else if (tid == Mm) {
        float s1 = 0.f;
        float d0 = o0 - off_gt[b * 2 + 0];
        float ad0 = fabsf(d0);
        s1 += (ad0 < 1.f) ? 0.5f * d0 * d0 : ad0 - 0.5f;
        float d1 = o1 - off_gt[b * 2 + 1];
        float ad1 = fabsf(d1);
        s1 += (ad1 < 1.f) ? 0.5f * d1 * d1 : ad1 - 0.5f;
        sl1_part[b] = s1;
    }
    __syncthreads();
    if (tid == 0) {
        float sx[6], sy[6];
        #pragma unroll
        for (int k = 0; k < 6; ++k) { sx[k] = tx[k]; sy[k] = ty[k]; }
        int cnt = 1;
        for (int i = 1; i < Mm; ++i) {
            bool close = false;
            #pragma unroll
            for (int k = 0; k < 6; ++k) {
                float dx = sx[k] - tx[i], dy = sy[k] - ty[i];
                close = close || ((k < cnt) && (dx * dx + dy * dy < 2.0f));
            }
            if (!close && cnt < 6) { sx[cnt] = tx[i]; sy[cnt] = ty[i]; cnt++; }
        }
        #pragma unroll
        for (int k = 0; k < 6; ++k) {
            out[(b * 6 + k) * 2 + 0] = sx[k];
            out[(b * 6 + k) * 2 + 1] = sy[k];
        }
    }
}

// ---------------- K5: final loss (parallel) ----------------
__global__ __launch_bounds__(256) void k_loss(const float* __restrict__ bce_part,
                                              const float* __restrict__ sl1_part,
                                              float* __restrict__ out) {
    __shared__ float redb[4], reds[4];
    int tid = threadIdx.x, wave = tid >> 6, lane = tid & 63;
    float sb = bce_part[tid];
    float ss = sl1_part[tid];
    #pragma unroll
    for (int mm = 1; mm < 64; mm <<= 1) { sb += __shfl_xor(sb, mm); ss += __shfl_xor(ss, mm); }
    if (lane == 0) { redb[wave] = sb; reds[wave] = ss; }
    __syncthreads();
    if (tid == 0) {
        float tb = ((redb[0] + redb[1]) + redb[2]) + redb[3];
        float ts = ((reds[0] + reds[1]) + reds[2]) + reds[3];
        out[0] = -tb / (float)(Bb * Nn) + ts / (float)(Bb * 2);
    }
}

extern "C" void kernel_launch(void* const* d_in, const int* in_sizes, int n_in,
                              void* d_out, int out_size, void* d_ws, size_t ws_size,
                              hipStream_t stream) {
    const float* feat  = (const float*)d_in[0];
    const float* cand  = (const float*)d_in[1];
    const float* mask  = (const float*)d_in[2];
    const float* gt    = (const float*)d_in[3];
    const float* ogt   = (const float*)d_in[4];
    const float* p_w1  = (const float*)d_in[5];
    const float* p_b1  = (const float*)d_in[6];
    const float* p_g1  = (const float*)d_in[7];
    const float* p_be1 = (const float*)d_in[8];
    const float* p_w2  = (const float*)d_in[9];
    const float* p_b2  = (const float*)d_in[10];
    const float* p_g2  = (const float*)d_in[11];
    const float* p_be2 = (const float*)d_in[12];
    const float* p_w3  = (const float*)d_in[13];
    const float* p_b3  = (const float*)d_in[14];
    const float* o_w1  = (const float*)d_in[15];
    const float* o_b1  = (const float*)d_in[16];
    const float* o_g1  = (const float*)d_in[17];
    const float* o_be1 = (const float*)d_in[18];
    const float* o_w2  = (const float*)d_in[19];
    const float* o_g2  = (const float*)d_in[20];   // NOTE: dict order puts o_g2 before o_b2
    const float* o_b2  = (const float*)d_in[21];
    const float* o_be2 = (const float*)d_in[22];
    const float* o_w3  = (const float*)d_in[23];
    const float* o_b3  = (const float*)d_in[24];

    float* ws       = (float*)d_ws;
    float* basep    = ws;                        // B*H
    float* baseo    = basep + Bb * Hh;           // B*H
    float* logits   = baseo + Bb * Hh;           // B*N
    float* bce_part = logits + (long)Bb * Nn;    // B
    float* sl1_part = bce_part + Bb;             // B
    int*   selidx_g = (int*)(sl1_part + Bb);     // B*M ints
    int*   gidx_g   = selidx_g + Bb * Mm;        // B ints

    float* out = (float*)d_out;                  // (B,6,2) floats then loss scalar

    k_base<<<Bb, 128, 0, stream>>>(feat, p_w1, p_b1, o_w1, o_b1, basep, baseo);
    k_mlp_p<<<Bb * 8, 256, 0, stream>>>(cand, basep,
        p_w1, p_g1, p_be1, p_w2, p_b2, p_g2, p_be2, p_w3, p_b3, logits);
    k_post<<<Bb, 256, 0, stream>>>(logits, mask, gt, bce_part, selidx_g, gidx_g);
    k_off<<<Bb, 64, 0, stream>>>(cand, baseo, selidx_g, gidx_g, ogt,
        o_w1, o_g1, o_be1, o_w2, o_b2, o_g2, o_be2, o_w3, o_b3, out, sl1_part);
    k_loss<<<1, 256, 0, stream>>>(bce_part, sl1_part, out + Bb * 6 * 2);
}

// Round 5
// 151.888 us; speedup vs baseline: 1.7319x; 1.1621x over previous
//
#include <hip/hip_runtime.h>
#include <hip/hip_bf16.h>
#include <math.h>

#define Bb 256
#define Nn 2048
#define Cc 128
#define Hh 64
#define Mm 50

// ---------------- K1: per-batch feat @ W1[:128] + b1 for BOTH MLPs ----------------
__global__ __launch_bounds__(128) void k_base(const float* __restrict__ feat,
                                              const float* __restrict__ p_w1,
                                              const float* __restrict__ p_b1,
                                              const float* __restrict__ o_w1,
                                              const float* __restrict__ o_b1,
                                              float* __restrict__ basep,
                                              float* __restrict__ baseo) {
    int b = blockIdx.x, tid = threadIdx.x;
    int k = tid & 63;
    bool lo = tid < 64;                     // wave-uniform select
    const float* w1 = lo ? p_w1 : o_w1;
    const float* b1 = lo ? p_b1 : o_b1;
    float* dst = lo ? basep : baseo;
    const float* f = feat + b * Cc;
    float s = b1[k];
    #pragma unroll 8
    for (int c = 0; c < Cc; ++c) s = fmaf(f[c], w1[c * Hh + k], s);
    dst[b * Hh + k] = s;
}

// ---------------- K2: prob MLP for all rows (FULL unroll -> all arrays in regs) ----------------
__global__ __launch_bounds__(256, 1) void k_mlp_p(
    const float* __restrict__ cand, const float* __restrict__ basep,
    const float* __restrict__ p_w1, const float* __restrict__ p_g1, const float* __restrict__ p_be1,
    const float* __restrict__ p_w2, const float* __restrict__ p_b2,
    const float* __restrict__ p_g2, const float* __restrict__ p_be2,
    const float* __restrict__ p_w3, const float* __restrict__ p_b3,
    float* __restrict__ logits)
{
    int tid = threadIdx.x;
    int b = blockIdx.x >> 3;            // 8 blocks x 256 threads = 2048 rows per batch
    int n = ((blockIdx.x & 7) << 8) + tid;
    long row = (long)b * Nn + n;
    float cx = cand[row * 2 + 0];
    float cy = cand[row * 2 + 1];
    const float* basev = basep + b * Hh;
    const float* u = p_w1 + 128 * Hh;
    const float* v = p_w1 + 129 * Hh;

    // layer 1 + LN + ReLU, a[] lives in registers (all indices compile-time)
    float a[Hh];
    float sum = 0.f, sq = 0.f;
    #pragma unroll
    for (int j = 0; j < Hh; ++j) {
        float t = fmaf(cy, v[j], fmaf(cx, u[j], basev[j]));
        a[j] = t;
        sum += t;
        sq = fmaf(t, t, sq);
    }
    float mu = sum * (1.f / Hh);
    float rstd = rsqrtf(sq * (1.f / Hh) - mu * mu + 1e-5f);
    #pragma unroll
    for (int j = 0; j < Hh; ++j)
        a[j] = fmaxf(fmaf((a[j] - mu) * rstd, p_g1[j], p_be1[j]), 0.f);

    // layer 2 — FULL unroll so a[j]/h[i] indices are compile-time (no scratch)
    float h[Hh];
    #pragma unroll
    for (int i = 0; i < Hh; ++i) h[i] = 0.f;
    #pragma unroll
    for (int j = 0; j < Hh; ++j) {
        float av = a[j];
        const float* w2r = p_w2 + j * Hh;
        #pragma unroll
        for (int i = 0; i < Hh; ++i) h[i] = fmaf(av, w2r[i], h[i]);
    }
    float sum2 = 0.f, sq2 = 0.f;
    #pragma unroll
    for (int i = 0; i < Hh; ++i) {
        float hv = h[i] + p_b2[i];
        h[i] = hv;
        sum2 += hv;
        sq2 = fmaf(hv, hv, sq2);
    }
    float mu2 = sum2 * (1.f / Hh);
    float rstd2 = rsqrtf(sq2 * (1.f / Hh) - mu2 * mu2 + 1e-5f);

    // head
    float lg = p_b3[0];
    #pragma unroll
    for (int i = 0; i < Hh; ++i) {
        float aa = fmaxf(fmaf((h[i] - mu2) * rstd2, p_g2[i], p_be2[i]), 0.f);
        lg = fmaf(aa, p_w3[i], lg);
    }
    logits[row] = lg;
}

// ---------------- K3: fused per-batch softmax + BCE partial + top-50 ----------------
__global__ __launch_bounds__(256) void k_post(
    const float* __restrict__ logits, const float* __restrict__ mask,
    const float* __restrict__ gt,
    float* __restrict__ bce_part, int* __restrict__ selidx_g, int* __restrict__ gidx_g)
{
    __shared__ float vals[Nn];          // p per candidate
    __shared__ float redf[4];
    __shared__ float wvv[4]; __shared__ int wvi[4];
    __shared__ int   gidx_sh;
    __shared__ int   wini_sh;
    __shared__ int   selidx[Mm];

    int b = blockIdx.x, tid = threadIdx.x;
    int wave = tid >> 6, lane = tid & 63;
    const float* lg = logits + (long)b * Nn;
    const float* mk = mask + (long)b * Nn;

    // ---- max ----
    float xv[8];
    float mx = -1e30f;
    #pragma unroll
    for (int k = 0; k < 8; ++k) {
        int n = tid + k * 256;
        xv[k] = lg[n] + mk[n];
        mx = fmaxf(mx, xv[k]);
    }
    #pragma unroll
    for (int m = 1; m < 64; m <<= 1) mx = fmaxf(mx, __shfl_xor(mx, m));
    if (lane == 0) redf[wave] = mx;
    __syncthreads();
    float m = fmaxf(fmaxf(redf[0], redf[1]), fmaxf(redf[2], redf[3]));
    __syncthreads();

    // ---- exp + sum ----
    float ev[8]; float es = 0.f;
    #pragma unroll
    for (int k = 0; k < 8; ++k) { ev[k] = expf(xv[k] - m); es += ev[k]; }
    #pragma unroll
    for (int mm = 1; mm < 64; mm <<= 1) es += __shfl_xor(es, mm);
    if (lane == 0) redf[wave] = es;
    __syncthreads();
    float invZ = 1.f / (((redf[0] + redf[1]) + redf[2]) + redf[3]);

    // ---- p, BCE partial, gt index ----
    const float* g = gt + (long)b * Nn;
    float bs = 0.f;
    #pragma unroll
    for (int k = 0; k < 8; ++k) {
        int n = tid + k * 256;
        float pv = ev[k] * invZ;
        vals[n] = pv;
        float gv = g[n];
        float lp = fmaxf(logf(pv), -100.f);
        float l1p = fmaxf(log1pf(-pv), -100.f);
        bs += gv * lp + (1.f - gv) * l1p;
        if (gv > 0.5f) gidx_sh = n;     // one-hot: exactly one writer
    }
    #pragma unroll
    for (int mm = 1; mm < 64; mm <<= 1) bs += __shfl_xor(bs, mm);
    if (lane == 0) redf[wave] = bs;
    __syncthreads();
    if (tid == 0) {
        bce_part[b] = ((redf[0] + redf[1]) + redf[2]) + redf[3];
        gidx_g[b] = gidx_sh;
    }

    // ---- top-50 (exact lax.top_k order: desc value, asc index on ties) ----
    float bv = -1.f; int bi = 0x7fffffff;
    #pragma unroll
    for (int k = 0; k < 8; ++k) {
        int n = tid + k * 256;          // ascending -> min idx kept on ties
        float v = vals[n];
        if (v > bv) { bv = v; bi = n; }
    }
    for (int it = 0; it < Mm; ++it) {
        float rv = bv; int ri = bi;
        #pragma unroll
        for (int mm = 1; mm < 64; mm <<= 1) {
            float v2 = __shfl_xor(rv, mm); int i2 = __shfl_xor(ri, mm);
            if (v2 > rv || (v2 == rv && i2 < ri)) { rv = v2; ri = i2; }
        }
        if (lane == 0) { wvv[wave] = rv; wvi[wave] = ri; }
        __syncthreads();                 // A: wvv/wvi visible to tid0
        if (tid == 0) {
            float wv = wvv[0]; int wi = wvi[0];
            #pragma unroll
            for (int k = 1; k < 4; ++k) {
                if (wvv[k] > wv || (wvv[k] == wv && wvi[k] < wi)) { wv = wvv[k]; wi = wvi[k]; }
            }
            wini_sh = wi;
            selidx[it] = wi;
        }
        __syncthreads();                 // B: wini_sh visible to all
        int wi = wini_sh;
        if ((wi & 255) == tid) {         // owner: remove + rescan local 8 (thread-local LDS slots)
            vals[wi] = -1.f;
            bv = -1.f; bi = 0x7fffffff;
            #pragma unroll
            for (int k = 0; k < 8; ++k) {
                int n = tid + k * 256;
                float v = vals[n];
                if (v > bv) { bv = v; bi = n; }
            }
        }
        // no barrier needed: next write to wvv/wini_sh happens after next barrier A/B
    }
    if (tid < Mm) selidx_g[b * Mm + tid] = selidx[tid];
}

// ---------------- offset MLP for one row (full unroll, bit-identical math) ----------------
__device__ __forceinline__ void off_mlp_row(
    long row, const float* __restrict__ cand, const float* __restrict__ basev,
    const float* __restrict__ o_w1, const float* __restrict__ o_g1, const float* __restrict__ o_be1,
    const float* __restrict__ o_w2, const float* __restrict__ o_b2,
    const float* __restrict__ o_g2, const float* __restrict__ o_be2,
    const float* __restrict__ o_w3, const float* __restrict__ o_b3,
    float& o0, float& o1)
{
    float cx = cand[row * 2 + 0];
    float cy = cand[row * 2 + 1];
    const float* u = o_w1 + 128 * Hh;
    const float* v = o_w1 + 129 * Hh;
    float a[Hh];
    float sum = 0.f, sq = 0.f;
    #pragma unroll
    for (int j = 0; j < Hh; ++j) {
        float t = fmaf(cy, v[j], fmaf(cx, u[j], basev[j]));
        a[j] = t;
        sum += t;
        sq = fmaf(t, t, sq);
    }
    float mu = sum * (1.f / Hh);
    float rstd = rsqrtf(sq * (1.f / Hh) - mu * mu + 1e-5f);
    #pragma unroll
    for (int j = 0; j < Hh; ++j)
        a[j] = fmaxf(fmaf((a[j] - mu) * rstd, o_g1[j], o_be1[j]), 0.f);
    float h[Hh];
    #pragma unroll
    for (int i = 0; i < Hh; ++i) h[i] = 0.f;
    #pragma unroll
    for (int j = 0; j < Hh; ++j) {
        float av = a[j];
        const float* w2r = o_w2 + j * Hh;
        #pragma unroll
        for (int i = 0; i < Hh; ++i) h[i] = fmaf(av, w2r[i], h[i]);
    }
    float sum2 = 0.f, sq2 = 0.f;
    #pragma unroll
    for (int i = 0; i < Hh; ++i) {
        float hv = h[i] + o_b2[i];
        h[i] = hv;
        sum2 += hv;
        sq2 = fmaf(hv, hv, sq2);
    }
    float mu2 = sum2 * (1.f / Hh);
    float rstd2 = rsqrtf(sq2 * (1.f / Hh) - mu2 * mu2 + 1e-5f);
    o0 = o_b3[0]; o1 = o_b3[1];
    #pragma unroll
    for (int i = 0; i < Hh; ++i) {
        float aa = fmaxf(fmaf((h[i] - mu2) * rstd2, o_g2[i], o_be2[i]), 0.f);
        o0 = fmaf(aa, o_w3[i * 2 + 0], o0);
        o1 = fmaf(aa, o_w3[i * 2 + 1], o1);
    }
}

// ---------------- K4: offset MLP on 51 rows/batch + gather + NMS + SL1 ----------------
__global__ __launch_bounds__(64, 1) void k_off(
    const float* __restrict__ cand, const float* __restrict__ baseo,
    const int* __restrict__ selidx_g, const int* __restrict__ gidx_g,
    const float* __restrict__ off_gt,
    const float* __restrict__ o_w1, const float* __restrict__ o_g1, const float* __restrict__ o_be1,
    const float* __restrict__ o_w2, const float* __restrict__ o_b2,
    const float* __restrict__ o_g2, const float* __restrict__ o_be2,
    const float* __restrict__ o_w3, const float* __restrict__ o_b3,
    float* __restrict__ out, float* __restrict__ sl1_part)
{
    __shared__ float tx[Mm], ty[Mm];
    int b = blockIdx.x, tid = threadIdx.x;
    const float* basev = baseo + b * Hh;

    int idx;
    if (tid < Mm)        idx = selidx_g[b * Mm + tid];
    else if (tid == Mm)  idx = gidx_g[b];
    else                 idx = 0;
    long row = (long)b * Nn + idx;

    float o0, o1;
    off_mlp_row(row, cand, basev, o_w1, o_g1, o_be1, o_w2, o_b2, o_g2, o_be2, o_w3, o_b3, o0, o1);

    if (tid < Mm) {
        tx[tid] = cand[row * 2 + 0] + o0;
        ty[tid] = cand[row * 2 + 1] + o1;
    } else if (tid == Mm) {
        float s1 = 0.f;
        float d0 = o0 - off_gt[b * 2 + 0];
        float ad0 = fabsf(d0);
        s1 += (ad0 < 1.f) ? 0.5f * d0 * d0 : ad0 - 0.5f;
        float d1 = o1 - off_gt[b * 2 + 1];
        float ad1 = fabsf(d1);
        s1 += (ad1 < 1.f) ? 0.5f * d1 * d1 : ad1 - 0.5f;
        sl1_part[b] = s1;
    }
    __syncthreads();
    if (tid == 0) {
        float sx[6], sy[6];
        #pragma unroll
        for (int k = 0; k < 6; ++k) { sx[k] = tx[k]; sy[k] = ty[k]; }
        int cnt = 1;
        for (int i = 1; i < Mm; ++i) {
            bool close = false;
            #pragma unroll
            for (int k = 0; k < 6; ++k) {
                float dx = sx[k] - tx[i], dy = sy[k] - ty[i];
                close = close || ((k < cnt) && (dx * dx + dy * dy < 2.0f));
            }
            if (!close && cnt < 6) { sx[cnt] = tx[i]; sy[cnt] = ty[i]; cnt++; }
        }
        #pragma unroll
        for (int k = 0; k < 6; ++k) {
            out[(b * 6 + k) * 2 + 0] = sx[k];
            out[(b * 6 + k) * 2 + 1] = sy[k];
        }
    }
}

// ---------------- K5: final loss (parallel) ----------------
__global__ __launch_bounds__(256) void k_loss(const float* __restrict__ bce_part,
                                              const float* __restrict__ sl1_part,
                                              float* __restrict__ out) {
    __shared__ float redb[4], reds[4];
    int tid = threadIdx.x, wave = tid >> 6, lane = tid & 63;
    float sb = bce_part[tid];
    float ss = sl1_part[tid];
    #pragma unroll
    for (int mm = 1; mm < 64; mm <<= 1) { sb += __shfl_xor(sb, mm); ss += __shfl_xor(ss, mm); }
    if (lane == 0) { redb[wave] = sb; reds[wave] = ss; }
    __syncthreads();
    if (tid == 0) {
        float tb = ((redb[0] + redb[1]) + redb[2]) + redb[3];
        float ts = ((reds[0] + reds[1]) + reds[2]) + reds[3];
        out[0] = -tb / (float)(Bb * Nn) + ts / (float)(Bb * 2);
    }
}

extern "C" void kernel_launch(void* const* d_in, const int* in_sizes, int n_in,
                              void* d_out, int out_size, void* d_ws, size_t ws_size,
                              hipStream_t stream) {
    const float* feat  = (const float*)d_in[0];
    const float* cand  = (const float*)d_in[1];
    const float* mask  = (const float*)d_in[2];
    const float* gt    = (const float*)d_in[3];
    const float* ogt   = (const float*)d_in[4];
    const float* p_w1  = (const float*)d_in[5];
    const float* p_b1  = (const float*)d_in[6];
    const float* p_g1  = (const float*)d_in[7];
    const float* p_be1 = (const float*)d_in[8];
    const float* p_w2  = (const float*)d_in[9];
    const float* p_b2  = (const float*)d_in[10];
    const float* p_g2  = (const float*)d_in[11];
    const float* p_be2 = (const float*)d_in[12];
    const float* p_w3  = (const float*)d_in[13];
    const float* p_b3  = (const float*)d_in[14];
    const float* o_w1  = (const float*)d_in[15];
    const float* o_b1  = (const float*)d_in[16];
    const float* o_g1  = (const float*)d_in[17];
    const float* o_be1 = (const float*)d_in[18];
    const float* o_w2  = (const float*)d_in[19];
    const float* o_g2  = (const float*)d_in[20];   // NOTE: dict order puts o_g2 before o_b2
    const float* o_b2  = (const float*)d_in[21];
    const float* o_be2 = (const float*)d_in[22];
    const float* o_w3  = (const float*)d_in[23];
    const float* o_b3  = (const float*)d_in[24];

    float* ws       = (float*)d_ws;
    float* basep    = ws;                        // B*H
    float* baseo    = basep + Bb * Hh;           // B*H
    float* logits   = baseo + Bb * Hh;           // B*N
    float* bce_part = logits + (long)Bb * Nn;    // B
    float* sl1_part = bce_part + Bb;             // B
    int*   selidx_g = (int*)(sl1_part + Bb);     // B*M ints
    int*   gidx_g   = selidx_g + Bb * Mm;        // B ints

    float* out = (float*)d_out;                  // (B,6,2) floats then loss scalar

    k_base<<<Bb, 128, 0, stream>>>(feat, p_w1, p_b1, o_w1, o_b1, basep, baseo);
    k_mlp_p<<<Bb * 8, 256, 0, stream>>>(cand, basep,
        p_w1, p_g1, p_be1, p_w2, p_b2, p_g2, p_be2, p_w3, p_b3, logits);
    k_post<<<Bb, 256, 0, stream>>>(logits, mask, gt, bce_part, selidx_g, gidx_g);
    k_off<<<Bb, 64, 0, stream>>>(cand, baseo, selidx_g, gidx_g, ogt,
        o_w1, o_g1, o_be1, o_w2, o_b2, o_g2, o_be2, o_w3, o_b3, out, sl1_part);
    k_loss<<<1, 256, 0, stream>>>(bce_part, sl1_part, out + Bb * 6 * 2);
}